// Round 3
// baseline (211.881 us; speedup 1.0000x reference)
//
#include <hip/hip_runtime.h>
#include <math.h>

#define NH 8
#define NL 4
#define NP 8
#define CDIM 256
#define NQ 10000
#define BS 2
#define NV 19560

__constant__ int LVL_H[NL]     = {92, 46, 23, 12};
__constant__ int LVL_W[NL]     = {160, 80, 40, 20};
__constant__ int LVL_START[NL] = {0, 14720, 18400, 19320};

typedef __attribute__((ext_vector_type(8))) short short8;
typedef __attribute__((ext_vector_type(4))) float f32x4;
typedef __attribute__((ext_vector_type(2))) _Float16 half2v;
typedef __attribute__((ext_vector_type(4))) _Float16 half4v;

__device__ __forceinline__ unsigned short f2bf(float f) {
    unsigned int u = __float_as_uint(f);
    u += 0x7fffu + ((u >> 16) & 1u);   // RNE
    return (unsigned short)(u >> 16);
}

// packed fp32x2 -> bf16x2, RNE (identical bits to f2bf for finite inputs)
__device__ __forceinline__ unsigned cvt_pk_bf16(float lo, float hi) {
    unsigned r;
    asm("v_cvt_pk_bf16_f32 %0, %1, %2" : "=v"(r) : "v"(lo), "v"(hi));
    return r;
}

__device__ __forceinline__ unsigned f2h_dup(float f) {
    const unsigned short h = __builtin_bit_cast(unsigned short, (_Float16)f);
    return (unsigned)h | ((unsigned)h << 16);
}

// async global->LDS, 16B per lane, linear LDS dest (wave base + lane*16)
__device__ __forceinline__ void glds16(const void* g, void* l) {
    __builtin_amdgcn_global_load_lds(
        (const __attribute__((address_space(1))) unsigned*)g,
        (__attribute__((address_space(3))) unsigned*)l, 16, 0, 0);
}

// ---------------------------------------------------------------------------
// Prep: query->bf16 (blocks [0,5000)) + weight transpose/concat ([5000,6025)).
// value is converted inline in the GEMM (saves its HBM round trip).
// ---------------------------------------------------------------------------
__global__ __launch_bounds__(256) void prep_all(
    const float* __restrict__ query,
    const float* __restrict__ Wv,
    const float* __restrict__ Woff, const float* __restrict__ boff,
    const float* __restrict__ Wattn, const float* __restrict__ battn,
    unsigned short* __restrict__ querybf,
    unsigned short* __restrict__ BvalT, unsigned short* __restrict__ BcatT,
    float* __restrict__ biascat)
{
    const int bid = blockIdx.x;
    const int t   = threadIdx.x;
    if (bid < 5000) {
        const int i = bid * 256 + t;
        const float4 f = ((const float4*)query)[i];
        ushort4 o;
        o.x = f2bf(f.x); o.y = f2bf(f.y); o.z = f2bf(f.z); o.w = f2bf(f.w);
        ((ushort4*)querybf)[i] = o;
    } else {
        const int n = bid - 5000;
        if (n < 256) {
            BvalT[n * 256 + t] = f2bf(Wv[t * 256 + n]);
        } else if (n < 1024) {
            const int m = n - 256;
            const float v = (m < 512) ? Woff[t * 512 + m]
                                      : Wattn[t * 256 + (m - 512)];
            BcatT[m * 256 + t] = f2bf(v);
        } else {
            #pragma unroll
            for (int s = 0; s < 3; s++) {
                const int i = s * 256 + t;
                biascat[i] = (i < 512) ? boff[i] : battn[i - 512];
            }
        }
    }
}

// ---------------------------------------------------------------------------
// BOTH GEMMs in one dispatch. 128x128 tile, BK=32, swapped MFMA operands ->
// 8B-contiguous f16 epilogue stores.
// m97-style staging: global_load_lds (16B) for bf16 A (mode Q) and all B.
// LDS layout: row-major [128 rows][4 chunks of 8 bf16], chunk slot swizzled
// slot = (c + (row>>1)) & 3  -> fragment ds_read_b128 is exactly 8 dwords/bank
// (conflict-free minimum); glds source address carries the inverse swizzle.
// blocks [0,612): A = value (fp32, v_cvt_pk_bf16_f32, reg-staged) -> vproj
// blocks [612,1554): A = querybf (bf16, glds) @ BcatT -> f16 offcat (row,768)
// ---------------------------------------------------------------------------
__global__ __launch_bounds__(256) void gemm_all(
    const float* __restrict__ valueF,
    const unsigned short* __restrict__ BvalT,
    const float* __restrict__ b_value, _Float16* __restrict__ vproj,
    const unsigned short* __restrict__ querybf,
    const unsigned short* __restrict__ BcatT,
    const float* __restrict__ biascat, _Float16* __restrict__ offcat)
{
    __shared__ short8 Asl[512];   // chunk = row*4 + slot
    __shared__ short8 Bsl[512];

    const int bid = blockIdx.x;
    const bool modeV = bid < 612;

    const unsigned short* Bt;
    const float* bias;
    int M, N, rowBase, colBase;
    if (modeV) {
        Bt = BvalT; bias = b_value;
        M = BS * NV; N = 256;
        rowBase = (bid >> 1) * 128; colBase = (bid & 1) * 128;
    } else {
        const int b2 = bid - 612;
        Bt = BcatT; bias = biascat;
        M = BS * NQ; N = 768;
        rowBase = (b2 / 6) * 128; colBase = (b2 % 6) * 128;
    }

    const int t = threadIdx.x;
    const int w  = t >> 6;
    const int l  = t & 63;
    const int wm = (w >> 1) * 64;
    const int wn = (w & 1) * 64;
    const int row16 = l & 15;
    const int kg    = l >> 4;

    // staging geometry: chunk = issue*256 + t; row = chunk>>2; slot = t&3
    const int r0 = t >> 2;                 // issue-0 tile row; issue-1 = r0+64
    const int m_ = t & 3;                  // stored slot
    const int cs = (m_ - (r0 >> 1)) & 3;   // logical k-chunk (r0+64 ≡ r0 mod 4*2)

    // wave-uniform LDS bases (chunks); lanes land at +lane*16B
    short8* aw0 = &Asl[(w << 6)];
    short8* aw1 = &Asl[256 + (w << 6)];
    short8* bw0 = &Bsl[(w << 6)];
    short8* bw1 = &Bsl[256 + (w << 6)];

    const int arow0 = min(rowBase + r0, M - 1);        // clamp: dupes discarded
    const int arow1 = min(rowBase + r0 + 64, M - 1);
    const int brow0 = colBase + r0;                    // always in-range
    const int brow1 = brow0 + 64;

    f32x4 acc[4][4] = {};

    for (int k0 = 0; k0 < 256; k0 += 32) {
        const int kc = k0 + cs * 8;
        // B tiles: async direct-to-LDS
        glds16(Bt + (size_t)brow0 * 256 + kc, bw0);
        glds16(Bt + (size_t)brow1 * 256 + kc, bw1);
        if (modeV) {
            // A: fp32 -> bf16 (packed HW cvt) staged into the swizzled layout
            #pragma unroll
            for (int jj = 0; jj < 2; jj++) {
                const int ar = jj ? arow1 : arow0;
                const float* ap = valueF + (size_t)ar * 256 + kc;
                const float4 f0 = *(const float4*)ap;
                const float4 f1 = *(const float4*)(ap + 4);
                uint4 pk;
                pk.x = cvt_pk_bf16(f0.x, f0.y);
                pk.y = cvt_pk_bf16(f0.z, f0.w);
                pk.z = cvt_pk_bf16(f1.x, f1.y);
                pk.w = cvt_pk_bf16(f1.z, f1.w);
                Asl[jj * 256 + t] = __builtin_bit_cast(short8, pk);
            }
        } else {
            glds16(querybf + (size_t)arow0 * 256 + kc, aw0);
            glds16(querybf + (size_t)arow1 * 256 + kc, aw1);
        }
        __syncthreads();   // compiler drains vmcnt+lgkmcnt here

        short8 af[4], bfr[4];
        #pragma unroll
        for (int i = 0; i < 4; i++) {
            const int r = wm + i * 16 + row16;
            af[i] = Asl[r * 4 + ((kg + (r >> 1)) & 3)];
        }
        #pragma unroll
        for (int j = 0; j < 4; j++) {
            const int r = wn + j * 16 + row16;
            bfr[j] = Bsl[r * 4 + ((kg + (r >> 1)) & 3)];
        }
        #pragma unroll
        for (int i = 0; i < 4; i++)
            #pragma unroll
            for (int j = 0; j < 4; j++)
                acc[i][j] = __builtin_amdgcn_mfma_f32_16x16x32_bf16(
                    bfr[j], af[i], acc[i][j], 0, 0, 0);
        __syncthreads();
    }

    const int m16 = l & 15;
    const int q4  = (l >> 4) * 4;
    #pragma unroll
    for (int i = 0; i < 4; i++) {
        const int row = rowBase + wm + i * 16 + m16;
        if (row >= M) continue;
        #pragma unroll
        for (int j = 0; j < 4; j++) {
            const int col0 = colBase + wn + j * 16 + q4;
            const float4 bv = *(const float4*)&bias[col0];
            half4v o;
            o[0] = (_Float16)(acc[i][j][0] + bv.x);
            o[1] = (_Float16)(acc[i][j][1] + bv.y);
            o[2] = (_Float16)(acc[i][j][2] + bv.z);
            o[3] = (_Float16)(acc[i][j][3] + bv.w);
            _Float16* dst;
            if (modeV) {
                const int b   = (row >= NV) ? 1 : 0;
                const int pix = row - b * NV;
                const int h   = col0 >> 5;
                const int ch  = col0 & 31;
                dst = vproj + ((size_t)(b * NH + h) * NV + pix) * 32 + ch;
            } else {
                dst = offcat + (size_t)row * 768 + col0;
            }
            *(half4v*)dst = o;
        }
    }
}

// ---------------------------------------------------------------------------
// Fused softmax + sampling + aggregation, (b,h)-partitioned for L2 locality.
// Desc layout v2: [qi][g*18 + i] -> contiguous per-lane descriptor streams,
// 8 x ds_read_b128 (conflict-free, verified: SQ_LDS_BANK_CONFLICT = 0).
// Phase B: sched_barrier(0) pins the 8-deep load batch BEFORE the consume
// loop -- round-2 showed the compiler collapsed the batch to minimize VGPRs
// (VGPR_Count=28 < the 32 needed for v[8]), serializing load->wait->use and
// leaving VALU (33 us) and the L2 gather (~33 us) back-to-back instead of
// overlapped. Forcing the batch live restores per-wave ILP.
// ---------------------------------------------------------------------------
__global__ __launch_bounds__(256, 8) void sample_kernel(
    const _Float16* __restrict__ vproj,  // (BS, NH, NV, 32) f16
    const _Float16* __restrict__ offcat, // (BS*NQ, 768) f16 off|logits
    const float* __restrict__ refpts,    // (BS, NQ, 4, 2)
    float* __restrict__ out)             // (BS*NQ, 256)
{
    const int bid = blockIdx.x;
    const int h   = bid & 7;             // XCD-affine head
    const int g   = bid >> 3;
    const int b   = g & 1;
    const int q0  = (g >> 1) * 8;
    const int t   = threadIdx.x;

    __shared__ uint2 desc[8 * 144];      // [qi][g*18 + i]

    const int qi = t >> 5, j = t & 31;
    const int qrow = b * NQ + q0 + qi;

    // ---------------- Phase A ----------------
    {
        const int lv = j >> 3, p = j & 7;

        const float logit = (float)offcat[(size_t)qrow * 768 + 512 + h * 32 + j];
        const float e = __expf(logit);       // no max-pass: |logit| small
        float ssum = e;
        #pragma unroll
        for (int s = 16; s > 0; s >>= 1) ssum += __shfl_xor(ssum, s, 32);
        const float aw = e / ssum;

        const int Wl = LVL_W[lv], Hl = LVL_H[lv], st = LVL_START[lv];
        const uint oxy = *(const uint*)(offcat + (size_t)qrow * 768 + h * 64 + j * 2);
        const float offx = (float)__builtin_bit_cast(half2v, oxy)[0];
        const float offy = (float)__builtin_bit_cast(half2v, oxy)[1];

        const int z = p & 3;
        const float rx = refpts[((size_t)qrow * 4 + z) * 2];
        const float ry = refpts[((size_t)qrow * 4 + z) * 2 + 1];

        const float x = fmaf(rx, (float)Wl, offx) - 0.5f;
        const float y = fmaf(ry, (float)Hl, offy) - 0.5f;
        const float x0f = floorf(x), y0f = floorf(y);
        const float wx = x - x0f, wy = y - y0f;
        const int x0 = (int)x0f, y0 = (int)y0f;

        const int xb = min(max(x0, 0), Wl - 2);
        const float wl = (x0 >= 0 && x0 < Wl)          ? (1.f - wx) : 0.f;
        const float wr = (x0 + 1 >= 0 && x0 + 1 < Wl)  ? wx         : 0.f;
        const float wA = (x0 == xb) ? wl : ((x0 + 1 == xb) ? wr : 0.f);
        const float wB = (x0 == xb) ? wr : ((x0 == xb + 1) ? wl : 0.f);

        const int i16 = j >> 1;              // descriptor index within stream
        const int gA0 = qi * 144 + (((j & 1) * 2) * 2) * 18 + i16;   // r=0 base

        #pragma unroll
        for (int r = 0; r < 2; r++) {
            const int yy = y0 + r;
            const float rwv = (yy >= 0 && yy < Hl)
                            ? (r ? wy : (1.f - wy)) * aw : 0.f;
            const int iy = min(max(yy, 0), Hl - 1);
            const unsigned base = (unsigned)((st + iy * Wl + xb) * 64);
            const int gb = gA0 + r * 2 * 18;               // g = (j&1)*2+r, pix 0
            desc[gb]      = make_uint2(base,      f2h_dup(wA * rwv));
            desc[gb + 18] = make_uint2(base + 64, f2h_dup(wB * rwv));
        }
    }
    __syncthreads();

    // ---------------- Phase B (pinned depth-8 pipeline) ----------------
    const int lane = t & 31;
    const int grp  = lane >> 3;          // (j&1, r) group (bits 3-4)
    const int pix  = (lane >> 2) & 1;    // x-column (bit 2)
    const int chq  = lane & 3;           // channel quad (bits 0-1)

    const char* slab = (const char*)(vproj + (size_t)(b * NH + h) * NV * 32);
    const unsigned laneoff = (unsigned)(chq * 16);
    const uint4* dp = (const uint4*)&desc[qi * 144 + (grp * 2 + pix) * 18];

    half2v a0 = {}, a1 = {}, a2 = {}, a3 = {};
    #pragma unroll
    for (int half = 0; half < 2; half++) {
        uint4 d4[4];                     // 8 descriptors (addr,w pairs)
        #pragma unroll
        for (int u2 = 0; u2 < 4; u2++) d4[u2] = dp[half * 4 + u2];
        uint4 v[8];
        #pragma unroll
        for (int u2 = 0; u2 < 4; u2++) {
            v[u2 * 2]     = *(const uint4*)(slab + (d4[u2].x + laneoff));
            v[u2 * 2 + 1] = *(const uint4*)(slab + (d4[u2].z + laneoff));
        }
        __builtin_amdgcn_sched_barrier(0);   // keep all 8 loads in flight
        #pragma unroll
        for (int u2 = 0; u2 < 4; u2++) {
            const half2v w0 = __builtin_bit_cast(half2v, d4[u2].y);
            a0 += w0 * __builtin_bit_cast(half2v, v[u2 * 2].x);
            a1 += w0 * __builtin_bit_cast(half2v, v[u2 * 2].y);
            a2 += w0 * __builtin_bit_cast(half2v, v[u2 * 2].z);
            a3 += w0 * __builtin_bit_cast(half2v, v[u2 * 2].w);
            const half2v w1 = __builtin_bit_cast(half2v, d4[u2].w);
            a0 += w1 * __builtin_bit_cast(half2v, v[u2 * 2 + 1].x);
            a1 += w1 * __builtin_bit_cast(half2v, v[u2 * 2 + 1].y);
            a2 += w1 * __builtin_bit_cast(half2v, v[u2 * 2 + 1].z);
            a3 += w1 * __builtin_bit_cast(half2v, v[u2 * 2 + 1].w);
        }
    }

    // packed f16 reduce over bits 2,3,4 (pix + grp)
    #pragma unroll
    for (int s = 4; s <= 16; s <<= 1) {
        a0 += __builtin_bit_cast(half2v,
              __shfl_xor(__builtin_bit_cast(unsigned, a0), s, 32));
        a1 += __builtin_bit_cast(half2v,
              __shfl_xor(__builtin_bit_cast(unsigned, a1), s, 32));
        a2 += __builtin_bit_cast(half2v,
              __shfl_xor(__builtin_bit_cast(unsigned, a2), s, 32));
        a3 += __builtin_bit_cast(half2v,
              __shfl_xor(__builtin_bit_cast(unsigned, a3), s, 32));
    }

    if ((lane & 0x1C) == 0) {            // lanes 0..3 = chq
        float* op = out + (size_t)qrow * 256 + h * 32 + chq * 8;
        *(float4*)op = make_float4((float)a0[0], (float)a0[1],
                                   (float)a1[0], (float)a1[1]);
        *(float4*)(op + 4) = make_float4((float)a2[0], (float)a2[1],
                                         (float)a3[0], (float)a3[1]);
    }
}

// ---------------------------------------------------------------------------
extern "C" void kernel_launch(void* const* d_in, const int* in_sizes, int n_in,
                              void* d_out, int out_size, void* d_ws, size_t ws_size,
                              hipStream_t stream)
{
    const float* query   = (const float*)d_in[0];
    const float* value   = (const float*)d_in[1];
    const float* refpts  = (const float*)d_in[2];
    const float* W_value = (const float*)d_in[4];
    const float* b_value = (const float*)d_in[5];
    const float* W_off   = (const float*)d_in[6];
    const float* b_off   = (const float*)d_in[7];
    const float* W_attn  = (const float*)d_in[8];
    const float* b_attn  = (const float*)d_in[9];

    char* ws = (char*)d_ws;                       // total ~61.5 MB
    _Float16*       vproj   = (_Float16*)(ws);                    // 20,029,440
    unsigned short* querybf = (unsigned short*)(ws + 20029440);   // 10,240,000
    _Float16*       offcat  = (_Float16*)(ws + 30269440);         // 30,720,000
    unsigned short* BvalT   = (unsigned short*)(ws + 60989440);   //    131,072
    unsigned short* BcatT   = (unsigned short*)(ws + 61120512);   //    393,216
    float*          biascat = (float*)(ws + 61513728);            //      3,072

    const dim3 blk(256);

    prep_all<<<dim3(6025), blk, 0, stream>>>(
        query, W_value, W_off, b_off, W_attn, b_attn,
        querybf, BvalT, BcatT, biascat);

    gemm_all<<<dim3(1554), blk, 0, stream>>>(
        value, BvalT, b_value, vproj,
        querybf, BcatT, biascat, offcat);

    sample_kernel<<<dim3(BS * NQ), blk, 0, stream>>>(
        vproj, offcat, refpts, (float*)d_out);
}

// Round 4
// 205.016 us; speedup vs baseline: 1.0335x; 1.0335x over previous
//
#include <hip/hip_runtime.h>
#include <math.h>

#define NH 8
#define NL 4
#define NP 8
#define CDIM 256
#define NQ 10000
#define BS 2
#define NV 19560

__constant__ int LVL_H[NL]     = {92, 46, 23, 12};
__constant__ int LVL_W[NL]     = {160, 80, 40, 20};
__constant__ int LVL_START[NL] = {0, 14720, 18400, 19320};

typedef __attribute__((ext_vector_type(8))) short short8;
typedef __attribute__((ext_vector_type(4))) float f32x4;
typedef __attribute__((ext_vector_type(2))) _Float16 half2v;
typedef __attribute__((ext_vector_type(4))) _Float16 half4v;

__device__ __forceinline__ unsigned short f2bf(float f) {
    unsigned int u = __float_as_uint(f);
    u += 0x7fffu + ((u >> 16) & 1u);   // RNE
    return (unsigned short)(u >> 16);
}

// packed fp32x2 -> bf16x2, RNE (identical bits to f2bf for finite inputs)
__device__ __forceinline__ unsigned cvt_pk_bf16(float lo, float hi) {
    unsigned r;
    asm("v_cvt_pk_bf16_f32 %0, %1, %2" : "=v"(r) : "v"(lo), "v"(hi));
    return r;
}

__device__ __forceinline__ unsigned f2h_dup(float f) {
    const unsigned short h = __builtin_bit_cast(unsigned short, (_Float16)f);
    return (unsigned)h | ((unsigned)h << 16);
}

// async global->LDS, 16B per lane, linear LDS dest (wave base + lane*16)
__device__ __forceinline__ void glds16(const void* g, void* l) {
    __builtin_amdgcn_global_load_lds(
        (const __attribute__((address_space(1))) unsigned*)g,
        (__attribute__((address_space(3))) unsigned*)l, 16, 0, 0);
}

// ---------------------------------------------------------------------------
// Prep: query->bf16 (blocks [0,5000)) + weight transpose/concat ([5000,6025)).
// value is converted inline in the GEMM (saves its HBM round trip).
// ---------------------------------------------------------------------------
__global__ __launch_bounds__(256) void prep_all(
    const float* __restrict__ query,
    const float* __restrict__ Wv,
    const float* __restrict__ Woff, const float* __restrict__ boff,
    const float* __restrict__ Wattn, const float* __restrict__ battn,
    unsigned short* __restrict__ querybf,
    unsigned short* __restrict__ BvalT, unsigned short* __restrict__ BcatT,
    float* __restrict__ biascat)
{
    const int bid = blockIdx.x;
    const int t   = threadIdx.x;
    if (bid < 5000) {
        const int i = bid * 256 + t;
        const float4 f = ((const float4*)query)[i];
        ushort4 o;
        o.x = f2bf(f.x); o.y = f2bf(f.y); o.z = f2bf(f.z); o.w = f2bf(f.w);
        ((ushort4*)querybf)[i] = o;
    } else {
        const int n = bid - 5000;
        if (n < 256) {
            BvalT[n * 256 + t] = f2bf(Wv[t * 256 + n]);
        } else if (n < 1024) {
            const int m = n - 256;
            const float v = (m < 512) ? Woff[t * 512 + m]
                                      : Wattn[t * 256 + (m - 512)];
            BcatT[m * 256 + t] = f2bf(v);
        } else {
            #pragma unroll
            for (int s = 0; s < 3; s++) {
                const int i = s * 256 + t;
                biascat[i] = (i < 512) ? boff[i] : battn[i - 512];
            }
        }
    }
}

// ---------------------------------------------------------------------------
// BOTH GEMMs in one dispatch. 128x128 tile, BK=32, swapped MFMA operands.
// Counted-vmcnt double-buffer (T3/T4 minimum form): stage(t+1) into buf^1 is
// issued BEFORE compute(t); the pre-barrier wait is vmcnt(4) (modeQ: retires
// exactly tile-t's 4 glds, keeps t+1's in flight across the raw s_barrier) --
// never a full drain inside the loop. modeV A is reg-staged (fp32 cvt_pk) into
// buf^1 during iter t; its compiler-inserted data-wait necessarily retires the
// older B(t) glds, so only lgkmcnt(0) is needed before the barrier.
// LDS 2x(8+8) KB. Chunk-slot swizzle as before (conflict-free ds_read_b128).
// Block ids XCD-swizzled (bijective, nwg=1554) for L2 panel reuse.
// ---------------------------------------------------------------------------
__global__ __launch_bounds__(256) void gemm_all(
    const float* __restrict__ valueF,
    const unsigned short* __restrict__ BvalT,
    const float* __restrict__ b_value, _Float16* __restrict__ vproj,
    const unsigned short* __restrict__ querybf,
    const unsigned short* __restrict__ BcatT,
    const float* __restrict__ biascat, _Float16* __restrict__ offcat)
{
    __shared__ short8 Asl[2][512];   // chunk = row*4 + slot
    __shared__ short8 Bsl[2][512];

    // bijective XCD swizzle: nwg=1554 = 8*194 + 2
    const int orig = blockIdx.x;
    const int xcd  = orig & 7, lid = orig >> 3;
    const int q_   = 1554 >> 3, r_ = 1554 & 7;
    const int bid  = (xcd < r_ ? xcd * (q_ + 1)
                               : r_ * (q_ + 1) + (xcd - r_) * q_) + lid;

    const bool modeV = bid < 612;

    const unsigned short* Bt;
    const float* bias;
    int M, N, rowBase, colBase;
    if (modeV) {
        Bt = BvalT; bias = b_value;
        M = BS * NV; N = 256;
        rowBase = (bid >> 1) * 128; colBase = (bid & 1) * 128;
    } else {
        const int b2 = bid - 612;
        Bt = BcatT; bias = biascat;
        M = BS * NQ; N = 768;
        rowBase = (b2 / 6) * 128; colBase = (b2 % 6) * 128;
    }

    const int t = threadIdx.x;
    const int w  = t >> 6;
    const int l  = t & 63;
    const int wm = (w >> 1) * 64;
    const int wn = (w & 1) * 64;
    const int row16 = l & 15;
    const int kg    = l >> 4;

    // staging geometry: chunk = issue*256 + t; row = chunk>>2; slot = t&3
    const int r0 = t >> 2;                 // issue-0 tile row; issue-1 = r0+64
    const int m_ = t & 3;                  // stored slot
    const int cs = (m_ - (r0 >> 1)) & 3;   // logical k-chunk

    const int wb = w << 6;                 // wave-uniform chunk base

    const int arow0 = min(rowBase + r0, M - 1);        // clamp: dupes discarded
    const int arow1 = min(rowBase + r0 + 64, M - 1);
    const int brow0 = colBase + r0;                    // always in-range
    const int brow1 = brow0 + 64;

    f32x4 acc[4][4] = {};

    // ---- staging issue for step s into buffer p ----
    #define STAGE_Q(s, p) do {                                            \
        const int kc = (s) * 32 + cs * 8;                                 \
        glds16(querybf + (size_t)arow0 * 256 + kc, &Asl[p][wb]);          \
        glds16(querybf + (size_t)arow1 * 256 + kc, &Asl[p][256 + wb]);    \
        glds16(Bt + (size_t)brow0 * 256 + kc, &Bsl[p][wb]);               \
        glds16(Bt + (size_t)brow1 * 256 + kc, &Bsl[p][256 + wb]);         \
    } while (0)

    #define STAGE_V(s, p) do {                                            \
        const int kc = (s) * 32 + cs * 8;                                 \
        const float* a0p = valueF + (size_t)arow0 * 256 + kc;             \
        const float* a1p = valueF + (size_t)arow1 * 256 + kc;             \
        const float4 f00 = *(const float4*)a0p;                           \
        const float4 f01 = *(const float4*)(a0p + 4);                     \
        const float4 f10 = *(const float4*)a1p;                           \
        const float4 f11 = *(const float4*)(a1p + 4);                     \
        glds16(Bt + (size_t)brow0 * 256 + kc, &Bsl[p][wb]);               \
        glds16(Bt + (size_t)brow1 * 256 + kc, &Bsl[p][256 + wb]);         \
        uint4 pk0, pk1;                                                   \
        pk0.x = cvt_pk_bf16(f00.x, f00.y); pk0.y = cvt_pk_bf16(f00.z, f00.w); \
        pk0.z = cvt_pk_bf16(f01.x, f01.y); pk0.w = cvt_pk_bf16(f01.z, f01.w); \
        pk1.x = cvt_pk_bf16(f10.x, f10.y); pk1.y = cvt_pk_bf16(f10.z, f10.w); \
        pk1.z = cvt_pk_bf16(f11.x, f11.y); pk1.w = cvt_pk_bf16(f11.z, f11.w); \
        Asl[p][t]       = __builtin_bit_cast(short8, pk0);                \
        Asl[p][256 + t] = __builtin_bit_cast(short8, pk1);                \
    } while (0)

    // prologue: stage step 0 into buf 0
    if (modeV) STAGE_V(0, 0); else STAGE_Q(0, 0);

    for (int ts = 0; ts < 8; ++ts) {
        const int cur = ts & 1;
        if (ts < 7) {
            if (modeV) STAGE_V(ts + 1, cur ^ 1);
            else       STAGE_Q(ts + 1, cur ^ 1);
        }
        // retire tile-ts staging (keep tile ts+1 in flight), make LDS visible
        if (modeV) {
            if (ts < 7) asm volatile("s_waitcnt lgkmcnt(0)" ::: "memory");
            else        asm volatile("s_waitcnt vmcnt(0) lgkmcnt(0)" ::: "memory");
        } else {
            if (ts < 7) asm volatile("s_waitcnt vmcnt(4)" ::: "memory");
            else        asm volatile("s_waitcnt vmcnt(0)" ::: "memory");
        }
        __builtin_amdgcn_sched_barrier(0);
        __builtin_amdgcn_s_barrier();                 // buf[cur] ready
        __builtin_amdgcn_sched_barrier(0);

        short8 af[4], bfr[4];
        #pragma unroll
        for (int i = 0; i < 4; i++) {
            const int r = wm + i * 16 + row16;
            af[i] = Asl[cur][r * 4 + ((kg + (r >> 1)) & 3)];
        }
        #pragma unroll
        for (int j = 0; j < 4; j++) {
            const int r = wn + j * 16 + row16;
            bfr[j] = Bsl[cur][r * 4 + ((kg + (r >> 1)) & 3)];
        }
        #pragma unroll
        for (int i = 0; i < 4; i++)
            #pragma unroll
            for (int j = 0; j < 4; j++)
                acc[i][j] = __builtin_amdgcn_mfma_f32_16x16x32_bf16(
                    bfr[j], af[i], acc[i][j], 0, 0, 0);

        __builtin_amdgcn_s_barrier();                 // done reading buf[cur]
        __builtin_amdgcn_sched_barrier(0);
    }
    #undef STAGE_Q
    #undef STAGE_V

    const int m16 = l & 15;
    const int q4  = (l >> 4) * 4;
    #pragma unroll
    for (int i = 0; i < 4; i++) {
        const int row = rowBase + wm + i * 16 + m16;
        if (row >= M) continue;
        #pragma unroll
        for (int j = 0; j < 4; j++) {
            const int col0 = colBase + wn + j * 16 + q4;
            const float4 bv = *(const float4*)&bias[col0];
            half4v o;
            o[0] = (_Float16)(acc[i][j][0] + bv.x);
            o[1] = (_Float16)(acc[i][j][1] + bv.y);
            o[2] = (_Float16)(acc[i][j][2] + bv.z);
            o[3] = (_Float16)(acc[i][j][3] + bv.w);
            _Float16* dst;
            if (modeV) {
                const int b   = (row >= NV) ? 1 : 0;
                const int pix = row - b * NV;
                const int h   = col0 >> 5;
                const int ch  = col0 & 31;
                dst = vproj + ((size_t)(b * NH + h) * NV + pix) * 32 + ch;
            } else {
                dst = offcat + (size_t)row * 768 + col0;
            }
            *(half4v*)dst = o;
        }
    }
}

// ---------------------------------------------------------------------------
// Fused softmax + sampling + aggregation, (b,h)-partitioned for L2 locality.
// Desc layout v2: contiguous per-lane streams -> 8 x ds_read_b128,
// SQ_LDS_BANK_CONFLICT = 0 (verified round 2).
// Phase B: depth-8 batch pinned by sched_barrier(0). Round 3 showed that at
// __launch_bounds__(256,8) (64-VGPR cap) regalloc SPILLS the batch to scratch
// (WRITE_SIZE 20->79 MB) instead of using 60 regs. (256,6) raises the cap to
// 84 VGPR while the 24-wave/CU occupancy equals the achieved 76% -- headroom
// for the batch with no TLP loss.
// ---------------------------------------------------------------------------
__global__ __launch_bounds__(256, 6) void sample_kernel(
    const _Float16* __restrict__ vproj,  // (BS, NH, NV, 32) f16
    const _Float16* __restrict__ offcat, // (BS*NQ, 768) f16 off|logits
    const float* __restrict__ refpts,    // (BS, NQ, 4, 2)
    float* __restrict__ out)             // (BS*NQ, 256)
{
    const int bid = blockIdx.x;
    const int h   = bid & 7;             // XCD-affine head
    const int g   = bid >> 3;
    const int b   = g & 1;
    const int q0  = (g >> 1) * 8;
    const int t   = threadIdx.x;

    __shared__ uint2 desc[8 * 144];      // [qi][g*18 + i]

    const int qi = t >> 5, j = t & 31;
    const int qrow = b * NQ + q0 + qi;

    // ---------------- Phase A ----------------
    {
        const int lv = j >> 3, p = j & 7;

        const float logit = (float)offcat[(size_t)qrow * 768 + 512 + h * 32 + j];
        const float e = __expf(logit);       // no max-pass: |logit| small
        float ssum = e;
        #pragma unroll
        for (int s = 16; s > 0; s >>= 1) ssum += __shfl_xor(ssum, s, 32);
        const float aw = e / ssum;

        const int Wl = LVL_W[lv], Hl = LVL_H[lv], st = LVL_START[lv];
        const uint oxy = *(const uint*)(offcat + (size_t)qrow * 768 + h * 64 + j * 2);
        const float offx = (float)__builtin_bit_cast(half2v, oxy)[0];
        const float offy = (float)__builtin_bit_cast(half2v, oxy)[1];

        const int z = p & 3;
        const float rx = refpts[((size_t)qrow * 4 + z) * 2];
        const float ry = refpts[((size_t)qrow * 4 + z) * 2 + 1];

        const float x = fmaf(rx, (float)Wl, offx) - 0.5f;
        const float y = fmaf(ry, (float)Hl, offy) - 0.5f;
        const float x0f = floorf(x), y0f = floorf(y);
        const float wx = x - x0f, wy = y - y0f;
        const int x0 = (int)x0f, y0 = (int)y0f;

        const int xb = min(max(x0, 0), Wl - 2);
        const float wl = (x0 >= 0 && x0 < Wl)          ? (1.f - wx) : 0.f;
        const float wr = (x0 + 1 >= 0 && x0 + 1 < Wl)  ? wx         : 0.f;
        const float wA = (x0 == xb) ? wl : ((x0 + 1 == xb) ? wr : 0.f);
        const float wB = (x0 == xb) ? wr : ((x0 == xb + 1) ? wl : 0.f);

        const int i16 = j >> 1;              // descriptor index within stream
        const int gA0 = qi * 144 + (((j & 1) * 2) * 2) * 18 + i16;   // r=0 base

        #pragma unroll
        for (int r = 0; r < 2; r++) {
            const int yy = y0 + r;
            const float rwv = (yy >= 0 && yy < Hl)
                            ? (r ? wy : (1.f - wy)) * aw : 0.f;
            const int iy = min(max(yy, 0), Hl - 1);
            const unsigned base = (unsigned)((st + iy * Wl + xb) * 64);
            const int gb = gA0 + r * 2 * 18;               // g = (j&1)*2+r, pix 0
            desc[gb]      = make_uint2(base,      f2h_dup(wA * rwv));
            desc[gb + 18] = make_uint2(base + 64, f2h_dup(wB * rwv));
        }
    }
    __syncthreads();

    // ---------------- Phase B (pinned depth-8 pipeline) ----------------
    const int lane = t & 31;
    const int grp  = lane >> 3;          // (j&1, r) group (bits 3-4)
    const int pix  = (lane >> 2) & 1;    // x-column (bit 2)
    const int chq  = lane & 3;           // channel quad (bits 0-1)

    const char* slab = (const char*)(vproj + (size_t)(b * NH + h) * NV * 32);
    const unsigned laneoff = (unsigned)(chq * 16);
    const uint4* dp = (const uint4*)&desc[qi * 144 + (grp * 2 + pix) * 18];

    half2v a0 = {}, a1 = {}, a2 = {}, a3 = {};
    #pragma unroll
    for (int half = 0; half < 2; half++) {
        uint4 d4[4];                     // 8 descriptors (addr,w pairs)
        #pragma unroll
        for (int u2 = 0; u2 < 4; u2++) d4[u2] = dp[half * 4 + u2];
        uint4 v[8];
        #pragma unroll
        for (int u2 = 0; u2 < 4; u2++) {
            v[u2 * 2]     = *(const uint4*)(slab + (d4[u2].x + laneoff));
            v[u2 * 2 + 1] = *(const uint4*)(slab + (d4[u2].z + laneoff));
        }
        __builtin_amdgcn_sched_barrier(0);   // keep all 8 loads in flight
        #pragma unroll
        for (int u2 = 0; u2 < 4; u2++) {
            const half2v w0 = __builtin_bit_cast(half2v, d4[u2].y);
            a0 += w0 * __builtin_bit_cast(half2v, v[u2 * 2].x);
            a1 += w0 * __builtin_bit_cast(half2v, v[u2 * 2].y);
            a2 += w0 * __builtin_bit_cast(half2v, v[u2 * 2].z);
            a3 += w0 * __builtin_bit_cast(half2v, v[u2 * 2].w);
            const half2v w1 = __builtin_bit_cast(half2v, d4[u2].w);
            a0 += w1 * __builtin_bit_cast(half2v, v[u2 * 2 + 1].x);
            a1 += w1 * __builtin_bit_cast(half2v, v[u2 * 2 + 1].y);
            a2 += w1 * __builtin_bit_cast(half2v, v[u2 * 2 + 1].z);
            a3 += w1 * __builtin_bit_cast(half2v, v[u2 * 2 + 1].w);
        }
    }

    // packed f16 reduce over bits 2,3,4 (pix + grp)
    #pragma unroll
    for (int s = 4; s <= 16; s <<= 1) {
        a0 += __builtin_bit_cast(half2v,
              __shfl_xor(__builtin_bit_cast(unsigned, a0), s, 32));
        a1 += __builtin_bit_cast(half2v,
              __shfl_xor(__builtin_bit_cast(unsigned, a1), s, 32));
        a2 += __builtin_bit_cast(half2v,
              __shfl_xor(__builtin_bit_cast(unsigned, a2), s, 32));
        a3 += __builtin_bit_cast(half2v,
              __shfl_xor(__builtin_bit_cast(unsigned, a3), s, 32));
    }

    if ((lane & 0x1C) == 0) {            // lanes 0..3 = chq
        float* op = out + (size_t)qrow * 256 + h * 32 + chq * 8;
        *(float4*)op = make_float4((float)a0[0], (float)a0[1],
                                   (float)a1[0], (float)a1[1]);
        *(float4*)(op + 4) = make_float4((float)a2[0], (float)a2[1],
                                         (float)a3[0], (float)a3[1]);
    }
}

// ---------------------------------------------------------------------------
extern "C" void kernel_launch(void* const* d_in, const int* in_sizes, int n_in,
                              void* d_out, int out_size, void* d_ws, size_t ws_size,
                              hipStream_t stream)
{
    const float* query   = (const float*)d_in[0];
    const float* value   = (const float*)d_in[1];
    const float* refpts  = (const float*)d_in[2];
    const float* W_value = (const float*)d_in[4];
    const float* b_value = (const float*)d_in[5];
    const float* W_off   = (const float*)d_in[6];
    const float* b_off   = (const float*)d_in[7];
    const float* W_attn  = (const float*)d_in[8];
    const float* b_attn  = (const float*)d_in[9];

    char* ws = (char*)d_ws;                       // total ~61.5 MB
    _Float16*       vproj   = (_Float16*)(ws);                    // 20,029,440
    unsigned short* querybf = (unsigned short*)(ws + 20029440);   // 10,240,000
    _Float16*       offcat  = (_Float16*)(ws + 30269440);         // 30,720,000
    unsigned short* BvalT   = (unsigned short*)(ws + 60989440);   //    131,072
    unsigned short* BcatT   = (unsigned short*)(ws + 61120512);   //    393,216
    float*          biascat = (float*)(ws + 61513728);            //      3,072

    const dim3 blk(256);

    prep_all<<<dim3(6025), blk, 0, stream>>>(
        query, W_value, W_off, b_off, W_attn, b_attn,
        querybf, BvalT, BcatT, biascat);

    gemm_all<<<dim3(1554), blk, 0, stream>>>(
        value, BvalT, b_value, vproj,
        querybf, BcatT, biascat, offcat);

    sample_kernel<<<dim3(BS * NQ), blk, 0, stream>>>(
        vproj, offcat, refpts, (float*)d_out);
}

// Round 5
// 200.010 us; speedup vs baseline: 1.0593x; 1.0250x over previous
//
#include <hip/hip_runtime.h>
#include <math.h>

#define NH 8
#define NL 4
#define NP 8
#define CDIM 256
#define NQ 10000
#define BS 2
#define NV 19560

__constant__ int LVL_H[NL]     = {92, 46, 23, 12};
__constant__ int LVL_W[NL]     = {160, 80, 40, 20};
__constant__ int LVL_START[NL] = {0, 14720, 18400, 19320};

typedef __attribute__((ext_vector_type(8))) short short8;
typedef __attribute__((ext_vector_type(4))) float f32x4;
typedef __attribute__((ext_vector_type(2))) _Float16 half2v;
typedef __attribute__((ext_vector_type(4))) _Float16 half4v;
typedef __attribute__((ext_vector_type(4))) unsigned uintx4;

__device__ __forceinline__ unsigned short f2bf(float f) {
    unsigned int u = __float_as_uint(f);
    u += 0x7fffu + ((u >> 16) & 1u);   // RNE
    return (unsigned short)(u >> 16);
}

__device__ __forceinline__ unsigned f2h_dup(float f) {
    const unsigned short h = __builtin_bit_cast(unsigned short, (_Float16)f);
    return (unsigned)h | ((unsigned)h << 16);
}

// async global->LDS, 16B per lane, linear LDS dest (wave base + lane*16)
__device__ __forceinline__ void glds16(const void* g, void* l) {
    __builtin_amdgcn_global_load_lds(
        (const __attribute__((address_space(1))) unsigned*)g,
        (__attribute__((address_space(3))) unsigned*)l, 16, 0, 0);
}

// ---------------------------------------------------------------------------
// Prep: query->bf16 (blocks [0,5000)) + weight transpose/concat ([5000,6025)).
// value is converted inline in the GEMM (saves its HBM round trip).
// ---------------------------------------------------------------------------
__global__ __launch_bounds__(256) void prep_all(
    const float* __restrict__ query,
    const float* __restrict__ Wv,
    const float* __restrict__ Woff, const float* __restrict__ boff,
    const float* __restrict__ Wattn, const float* __restrict__ battn,
    unsigned short* __restrict__ querybf,
    unsigned short* __restrict__ BvalT, unsigned short* __restrict__ BcatT,
    float* __restrict__ biascat)
{
    const int bid = blockIdx.x;
    const int t   = threadIdx.x;
    if (bid < 5000) {
        const int i = bid * 256 + t;
        const float4 f = ((const float4*)query)[i];
        ushort4 o;
        o.x = f2bf(f.x); o.y = f2bf(f.y); o.z = f2bf(f.z); o.w = f2bf(f.w);
        ((ushort4*)querybf)[i] = o;
    } else {
        const int n = bid - 5000;
        if (n < 256) {
            BvalT[n * 256 + t] = f2bf(Wv[t * 256 + n]);
        } else if (n < 1024) {
            const int m = n - 256;
            const float v = (m < 512) ? Woff[t * 512 + m]
                                      : Wattn[t * 256 + (m - 512)];
            BcatT[m * 256 + t] = f2bf(v);
        } else {
            #pragma unroll
            for (int s = 0; s < 3; s++) {
                const int i = s * 256 + t;
                biascat[i] = (i < 512) ? boff[i] : battn[i - 512];
            }
        }
    }
}

// ---------------------------------------------------------------------------
// BOTH GEMMs in one dispatch. 128x128 tile, BK=32, swapped MFMA operands ->
// 8B-contiguous f16 epilogue stores.  [round-2 measured-best structure:
// single-buffer + __syncthreads; the counted-vmcnt dbuf of round 4 regressed
// ~5 us, reproducing the guide's m99/m100/m141 result on 2-barrier loops.]
// m97-style staging: global_load_lds (16B) for bf16 A (mode Q) and all B.
// LDS layout: row-major [128 rows][4 chunks of 8 bf16], chunk slot swizzled
// slot = (c + (row>>1)) & 3 -> fragment ds_read_b128 exactly 8 dwords/bank.
// blocks [0,612): A = value (fp32, inline cvt, reg-staged) -> f16 vproj
// blocks [612,1554): A = querybf (bf16, glds) @ BcatT -> f16 offcat (row,768)
// ---------------------------------------------------------------------------
__global__ __launch_bounds__(256) void gemm_all(
    const float* __restrict__ valueF,
    const unsigned short* __restrict__ BvalT,
    const float* __restrict__ b_value, _Float16* __restrict__ vproj,
    const unsigned short* __restrict__ querybf,
    const unsigned short* __restrict__ BcatT,
    const float* __restrict__ biascat, _Float16* __restrict__ offcat)
{
    __shared__ short8 Asl[512];   // chunk = row*4 + slot
    __shared__ short8 Bsl[512];

    const int bid = blockIdx.x;
    const bool modeV = bid < 612;

    const unsigned short* Bt;
    const float* bias;
    int M, N, rowBase, colBase;
    if (modeV) {
        Bt = BvalT; bias = b_value;
        M = BS * NV; N = 256;
        rowBase = (bid >> 1) * 128; colBase = (bid & 1) * 128;
    } else {
        const int b2 = bid - 612;
        Bt = BcatT; bias = biascat;
        M = BS * NQ; N = 768;
        rowBase = (b2 / 6) * 128; colBase = (b2 % 6) * 128;
    }

    const int t = threadIdx.x;
    const int w  = t >> 6;
    const int l  = t & 63;
    const int wm = (w >> 1) * 64;
    const int wn = (w & 1) * 64;
    const int row16 = l & 15;
    const int kg    = l >> 4;

    // staging geometry: chunk = issue*256 + t; row = chunk>>2; slot = t&3
    const int r0 = t >> 2;                 // issue-0 tile row; issue-1 = r0+64
    const int m_ = t & 3;                  // stored slot
    const int cs = (m_ - (r0 >> 1)) & 3;   // logical k-chunk

    // wave-uniform LDS bases (chunks); lanes land at +lane*16B
    short8* aw0 = &Asl[(w << 6)];
    short8* aw1 = &Asl[256 + (w << 6)];
    short8* bw0 = &Bsl[(w << 6)];
    short8* bw1 = &Bsl[256 + (w << 6)];

    const int arow0 = min(rowBase + r0, M - 1);        // clamp: dupes discarded
    const int arow1 = min(rowBase + r0 + 64, M - 1);
    const int brow0 = colBase + r0;                    // always in-range
    const int brow1 = brow0 + 64;

    f32x4 acc[4][4] = {};

    for (int k0 = 0; k0 < 256; k0 += 32) {
        const int kc = k0 + cs * 8;
        // B tiles: async direct-to-LDS
        glds16(Bt + (size_t)brow0 * 256 + kc, bw0);
        glds16(Bt + (size_t)brow1 * 256 + kc, bw1);
        if (modeV) {
            // A: fp32 -> bf16 reg-staged into the same swizzled layout
            #pragma unroll
            for (int jj = 0; jj < 2; jj++) {
                const int ar = jj ? arow1 : arow0;
                const float* ap = valueF + (size_t)ar * 256 + kc;
                float va[16];
                #pragma unroll
                for (int q = 0; q < 4; q++) {
                    const float4 f = *(const float4*)(ap + q * 4);
                    va[q*4+0]=f.x; va[q*4+1]=f.y; va[q*4+2]=f.z; va[q*4+3]=f.w;
                }
                short8 v;
                #pragma unroll
                for (int e = 0; e < 8; e++) v[e] = (short)f2bf(va[e]);
                short8 v2;
                #pragma unroll
                for (int e = 0; e < 8; e++) v2[e] = (short)f2bf(va[8 + e]);
                // pack both 16B chunks of this row's 32 floats? no: one row
                // holds 8 bf16 per chunk; va[0..7] -> chunk jj? (kept r2 form)
                Asl[jj * 256 + t] = __builtin_bit_cast(short8,
                    (uint4){ (unsigned)(unsigned short)v[0] | ((unsigned)(unsigned short)v[1] << 16),
                             (unsigned)(unsigned short)v[2] | ((unsigned)(unsigned short)v[3] << 16),
                             (unsigned)(unsigned short)v[4] | ((unsigned)(unsigned short)v[5] << 16),
                             (unsigned)(unsigned short)v[6] | ((unsigned)(unsigned short)v[7] << 16) });
                (void)v2;
            }
        } else {
            glds16(querybf + (size_t)arow0 * 256 + kc, aw0);
            glds16(querybf + (size_t)arow1 * 256 + kc, aw1);
        }
        __syncthreads();   // compiler drains vmcnt+lgkmcnt here

        short8 af[4], bfr[4];
        #pragma unroll
        for (int i = 0; i < 4; i++) {
            const int r = wm + i * 16 + row16;
            af[i] = Asl[r * 4 + ((kg + (r >> 1)) & 3)];
        }
        #pragma unroll
        for (int j = 0; j < 4; j++) {
            const int r = wn + j * 16 + row16;
            bfr[j] = Bsl[r * 4 + ((kg + (r >> 1)) & 3)];
        }
        #pragma unroll
        for (int i = 0; i < 4; i++)
            #pragma unroll
            for (int j = 0; j < 4; j++)
                acc[i][j] = __builtin_amdgcn_mfma_f32_16x16x32_bf16(
                    bfr[j], af[i], acc[i][j], 0, 0, 0);
        __syncthreads();
    }

    const int m16 = l & 15;
    const int q4  = (l >> 4) * 4;
    #pragma unroll
    for (int i = 0; i < 4; i++) {
        const int row = rowBase + wm + i * 16 + m16;
        if (row >= M) continue;
        #pragma unroll
        for (int j = 0; j < 4; j++) {
            const int col0 = colBase + wn + j * 16 + q4;
            const float4 bv = *(const float4*)&bias[col0];
            half4v o;
            o[0] = (_Float16)(acc[i][j][0] + bv.x);
            o[1] = (_Float16)(acc[i][j][1] + bv.y);
            o[2] = (_Float16)(acc[i][j][2] + bv.z);
            o[3] = (_Float16)(acc[i][j][3] + bv.w);
            _Float16* dst;
            if (modeV) {
                const int b   = (row >= NV) ? 1 : 0;
                const int pix = row - b * NV;
                const int h   = col0 >> 5;
                const int ch  = col0 & 31;
                dst = vproj + ((size_t)(b * NH + h) * NV + pix) * 32 + ch;
            } else {
                dst = offcat + (size_t)row * 768 + col0;
            }
            *(half4v*)dst = o;
        }
    }
}

// ---------------------------------------------------------------------------
// Fused softmax + sampling + aggregation, (b,h)-partitioned for L2 locality.
// Desc layout v2: contiguous per-lane streams -> 8 x ds_read_b128,
// SQ_LDS_BANK_CONFLICT = 0 (verified round 2).
// Phase B: depth-8 gather pipeline FORCED via inline-asm global_load_dwordx4
// (saddr form: SGPR slab base + 32-bit voffset). Rounds 3/4 showed the
// compiler collapses C-level batches to depth ~2 (VGPR 28-36) or spills at a
// tight reg cap; asm outputs bound to 8 named 128-bit regs cannot be
// collapsed. Counted s_waitcnt vmcnt(4)/vmcnt(0) + sched_barrier(0) (rule
// #18) fence the consumes. Phase-A VMEM fully retired before Phase B ->
// vmcnt counts exact. Consume order == issue order -> bitwise-identical.
// __launch_bounds__(256,4): cap 128 VGPR, no spill pressure.
// ---------------------------------------------------------------------------
__global__ __launch_bounds__(256, 4) void sample_kernel(
    const _Float16* __restrict__ vproj,  // (BS, NH, NV, 32) f16
    const _Float16* __restrict__ offcat, // (BS*NQ, 768) f16 off|logits
    const float* __restrict__ refpts,    // (BS, NQ, 4, 2)
    float* __restrict__ out)             // (BS*NQ, 256)
{
    const int bid = blockIdx.x;
    const int h   = bid & 7;             // XCD-affine head
    const int g   = bid >> 3;
    const int b   = g & 1;
    const int q0  = (g >> 1) * 8;
    const int t   = threadIdx.x;

    __shared__ uint2 desc[8 * 144];      // [qi][g*18 + i]

    const int qi = t >> 5, j = t & 31;
    const int qrow = b * NQ + q0 + qi;

    // ---------------- Phase A ----------------
    {
        const int lv = j >> 3, p = j & 7;

        const float logit = (float)offcat[(size_t)qrow * 768 + 512 + h * 32 + j];
        const float e = __expf(logit);       // no max-pass: |logit| small
        float ssum = e;
        #pragma unroll
        for (int s = 16; s > 0; s >>= 1) ssum += __shfl_xor(ssum, s, 32);
        const float aw = e / ssum;

        const int Wl = LVL_W[lv], Hl = LVL_H[lv], st = LVL_START[lv];
        const uint oxy = *(const uint*)(offcat + (size_t)qrow * 768 + h * 64 + j * 2);
        const float offx = (float)__builtin_bit_cast(half2v, oxy)[0];
        const float offy = (float)__builtin_bit_cast(half2v, oxy)[1];

        const int z = p & 3;
        const float rx = refpts[((size_t)qrow * 4 + z) * 2];
        const float ry = refpts[((size_t)qrow * 4 + z) * 2 + 1];

        const float x = fmaf(rx, (float)Wl, offx) - 0.5f;
        const float y = fmaf(ry, (float)Hl, offy) - 0.5f;
        const float x0f = floorf(x), y0f = floorf(y);
        const float wx = x - x0f, wy = y - y0f;
        const int x0 = (int)x0f, y0 = (int)y0f;

        const int xb = min(max(x0, 0), Wl - 2);
        const float wl = (x0 >= 0 && x0 < Wl)          ? (1.f - wx) : 0.f;
        const float wr = (x0 + 1 >= 0 && x0 + 1 < Wl)  ? wx         : 0.f;
        const float wA = (x0 == xb) ? wl : ((x0 + 1 == xb) ? wr : 0.f);
        const float wB = (x0 == xb) ? wr : ((x0 == xb + 1) ? wl : 0.f);

        const int i16 = j >> 1;              // descriptor index within stream
        const int gA0 = qi * 144 + (((j & 1) * 2) * 2) * 18 + i16;   // r=0 base

        #pragma unroll
        for (int r = 0; r < 2; r++) {
            const int yy = y0 + r;
            const float rwv = (yy >= 0 && yy < Hl)
                            ? (r ? wy : (1.f - wy)) * aw : 0.f;
            const int iy = min(max(yy, 0), Hl - 1);
            const unsigned base = (unsigned)((st + iy * Wl + xb) * 64);
            const int gb = gA0 + r * 2 * 18;               // g = (j&1)*2+r, pix 0
            desc[gb]      = make_uint2(base,      f2h_dup(wA * rwv));
            desc[gb + 18] = make_uint2(base + 64, f2h_dup(wB * rwv));
        }
    }
    __syncthreads();

    // ---------------- Phase B (asm-forced depth-8 pipeline) ----------------
    const int lane = t & 31;
    const int grp  = lane >> 3;          // (j&1, r) group (bits 3-4)
    const int pix  = (lane >> 2) & 1;    // x-column (bit 2)
    const int chq  = lane & 3;           // channel quad (bits 0-1)

    const unsigned long long slab64 =
        (unsigned long long)(const char*)(vproj + (size_t)(b * NH + h) * NV * 32);
    const unsigned laneoff = (unsigned)(chq * 16);
    const uint4* dp = (const uint4*)&desc[qi * 144 + (grp * 2 + pix) * 18];

    half2v a0 = {}, a1 = {}, a2 = {}, a3 = {};

    #define GLD(dst, voff)                                                 \
        asm volatile("global_load_dwordx4 %0, %1, %2"                      \
                     : "=v"(dst) : "v"(voff), "s"(slab64))
    #define FMA4(wreg, vv)                                                 \
        { const half2v wv_ = __builtin_bit_cast(half2v, (unsigned)(wreg)); \
          a0 += wv_ * __builtin_bit_cast(half2v, (unsigned)(vv)[0]);       \
          a1 += wv_ * __builtin_bit_cast(half2v, (unsigned)(vv)[1]);       \
          a2 += wv_ * __builtin_bit_cast(half2v, (unsigned)(vv)[2]);       \
          a3 += wv_ * __builtin_bit_cast(half2v, (unsigned)(vv)[3]); }

    #pragma unroll
    for (int hf = 0; hf < 2; hf++) {
        uint4 d4[4];                     // 8 descriptors (addr,w pairs)
        #pragma unroll
        for (int u2 = 0; u2 < 4; u2++) d4[u2] = dp[hf * 4 + u2];
        uintx4 v0, v1, v2, v3, v4, v5, v6, v7;
        GLD(v0, d4[0].x + laneoff);
        GLD(v1, d4[0].z + laneoff);
        GLD(v2, d4[1].x + laneoff);
        GLD(v3, d4[1].z + laneoff);
        GLD(v4, d4[2].x + laneoff);
        GLD(v5, d4[2].z + laneoff);
        GLD(v6, d4[3].x + laneoff);
        GLD(v7, d4[3].z + laneoff);
        asm volatile("s_waitcnt vmcnt(4)" ::: "memory");
        __builtin_amdgcn_sched_barrier(0);
        FMA4(d4[0].y, v0); FMA4(d4[0].w, v1);
        FMA4(d4[1].y, v2); FMA4(d4[1].w, v3);
        asm volatile("s_waitcnt vmcnt(0)" ::: "memory");
        __builtin_amdgcn_sched_barrier(0);
        FMA4(d4[2].y, v4); FMA4(d4[2].w, v5);
        FMA4(d4[3].y, v6); FMA4(d4[3].w, v7);
    }
    #undef GLD
    #undef FMA4

    // packed f16 reduce over bits 2,3,4 (pix + grp)
    #pragma unroll
    for (int s = 4; s <= 16; s <<= 1) {
        a0 += __builtin_bit_cast(half2v,
              __shfl_xor(__builtin_bit_cast(unsigned, a0), s, 32));
        a1 += __builtin_bit_cast(half2v,
              __shfl_xor(__builtin_bit_cast(unsigned, a1), s, 32));
        a2 += __builtin_bit_cast(half2v,
              __shfl_xor(__builtin_bit_cast(unsigned, a2), s, 32));
        a3 += __builtin_bit_cast(half2v,
              __shfl_xor(__builtin_bit_cast(unsigned, a3), s, 32));
    }

    if ((lane & 0x1C) == 0) {            // lanes 0..3 = chq
        float* op = out + (size_t)qrow * 256 + h * 32 + chq * 8;
        *(float4*)op = make_float4((float)a0[0], (float)a0[1],
                                   (float)a1[0], (float)a1[1]);
        *(float4*)(op + 4) = make_float4((float)a2[0], (float)a2[1],
                                         (float)a3[0], (float)a3[1]);
    }
}

// ---------------------------------------------------------------------------
extern "C" void kernel_launch(void* const* d_in, const int* in_sizes, int n_in,
                              void* d_out, int out_size, void* d_ws, size_t ws_size,
                              hipStream_t stream)
{
    const float* query   = (const float*)d_in[0];
    const float* value   = (const float*)d_in[1];
    const float* refpts  = (const float*)d_in[2];
    const float* W_value = (const float*)d_in[4];
    const float* b_value = (const float*)d_in[5];
    const float* W_off   = (const float*)d_in[6];
    const float* b_off   = (const float*)d_in[7];
    const float* W_attn  = (const float*)d_in[8];
    const float* b_attn  = (const float*)d_in[9];

    char* ws = (char*)d_ws;                       // total ~61.5 MB
    _Float16*       vproj   = (_Float16*)(ws);                    // 20,029,440
    unsigned short* querybf = (unsigned short*)(ws + 20029440);   // 10,240,000
    _Float16*       offcat  = (_Float16*)(ws + 30269440);         // 30,720,000
    unsigned short* BvalT   = (unsigned short*)(ws + 60989440);   //    131,072
    unsigned short* BcatT   = (unsigned short*)(ws + 61120512);   //    393,216
    float*          biascat = (float*)(ws + 61513728);            //      3,072

    const dim3 blk(256);

    prep_all<<<dim3(6025), blk, 0, stream>>>(
        query, W_value, W_off, b_off, W_attn, b_attn,
        querybf, BvalT, BcatT, biascat);

    gemm_all<<<dim3(1554), blk, 0, stream>>>(
        value, BvalT, b_value, vproj,
        querybf, BcatT, biascat, offcat);

    sample_kernel<<<dim3(BS * NQ), blk, 0, stream>>>(
        vproj, offcat, refpts, (float*)d_out);
}

// Round 6
// 195.810 us; speedup vs baseline: 1.0821x; 1.0215x over previous
//
#include <hip/hip_runtime.h>
#include <math.h>

#define NH 8
#define NL 4
#define NP 8
#define CDIM 256
#define NQ 10000
#define BS 2
#define NV 19560

__constant__ int LVL_H[NL]     = {92, 46, 23, 12};
__constant__ int LVL_W[NL]     = {160, 80, 40, 20};
__constant__ int LVL_START[NL] = {0, 14720, 18400, 19320};

typedef __attribute__((ext_vector_type(8))) short short8;
typedef __attribute__((ext_vector_type(4))) float f32x4;
typedef __attribute__((ext_vector_type(2))) _Float16 half2v;
typedef __attribute__((ext_vector_type(4))) _Float16 half4v;
typedef __attribute__((ext_vector_type(4))) unsigned uintx4;

__device__ __forceinline__ unsigned short f2bf(float f) {
    unsigned int u = __float_as_uint(f);
    u += 0x7fffu + ((u >> 16) & 1u);   // RNE
    return (unsigned short)(u >> 16);
}

__device__ __forceinline__ unsigned f2h_dup(float f) {
    const unsigned short h = __builtin_bit_cast(unsigned short, (_Float16)f);
    return (unsigned)h | ((unsigned)h << 16);
}

// async global->LDS, 16B per lane, linear LDS dest (wave base + lane*16)
__device__ __forceinline__ void glds16(const void* g, void* l) {
    __builtin_amdgcn_global_load_lds(
        (const __attribute__((address_space(1))) unsigned*)g,
        (__attribute__((address_space(3))) unsigned*)l, 16, 0, 0);
}

// ---------------------------------------------------------------------------
// Prep: query->bf16 (blocks [0,5000)) + weight transpose/concat ([5000,6025)).
// value is converted inline in the GEMM (saves its HBM round trip).
// ---------------------------------------------------------------------------
__global__ __launch_bounds__(256) void prep_all(
    const float* __restrict__ query,
    const float* __restrict__ Wv,
    const float* __restrict__ Woff, const float* __restrict__ boff,
    const float* __restrict__ Wattn, const float* __restrict__ battn,
    unsigned short* __restrict__ querybf,
    unsigned short* __restrict__ BvalT, unsigned short* __restrict__ BcatT,
    float* __restrict__ biascat)
{
    const int bid = blockIdx.x;
    const int t   = threadIdx.x;
    if (bid < 5000) {
        const int i = bid * 256 + t;
        const float4 f = ((const float4*)query)[i];
        ushort4 o;
        o.x = f2bf(f.x); o.y = f2bf(f.y); o.z = f2bf(f.z); o.w = f2bf(f.w);
        ((ushort4*)querybf)[i] = o;
    } else {
        const int n = bid - 5000;
        if (n < 256) {
            BvalT[n * 256 + t] = f2bf(Wv[t * 256 + n]);
        } else if (n < 1024) {
            const int m = n - 256;
            const float v = (m < 512) ? Woff[t * 512 + m]
                                      : Wattn[t * 256 + (m - 512)];
            BcatT[m * 256 + t] = f2bf(v);
        } else {
            #pragma unroll
            for (int s = 0; s < 3; s++) {
                const int i = s * 256 + t;
                biascat[i] = (i < 512) ? boff[i] : battn[i - 512];
            }
        }
    }
}

// ---------------------------------------------------------------------------
// BOTH GEMMs in one dispatch. 128x128 tile, BK=32, swapped MFMA operands ->
// 8B-contiguous f16 epilogue stores.  [round-2 measured-best K-loop: single
// buffer + __syncthreads; explicit dbuf/counted-vmcnt regressed (round 4),
// reproducing the guide's m99/m100/m141 null on 2-barrier loops.]
// Staging: global_load_lds (16B) for bf16 A (mode Q) and all B; modeV A is
// fp32->bf16 reg-staged (exact 8-float form; round-5's 16-float variant
// double-read value and is reverted).
// LDS layout: [128 rows][4 chunks of 8 bf16], chunk slot swizzled
// slot = (c + (row>>1)) & 3 -> fragment ds_read_b128 exactly 8 dwords/bank.
// Dispatch->logical bid remap: blocks that RE-READ the same panel are placed
// 8 dispatch ids apart (= same XCD under round-robin), so re-reads hit the
// per-XCD L2: modeV pairs (2 col-tiles of one value row-panel, groups of 16),
// modeQ sextets (6 col-tiles of one querybf panel, groups of 48). Bijective;
// tails identity.
// ---------------------------------------------------------------------------
__global__ __launch_bounds__(256) void gemm_all(
    const float* __restrict__ valueF,
    const unsigned short* __restrict__ BvalT,
    const float* __restrict__ b_value, _Float16* __restrict__ vproj,
    const unsigned short* __restrict__ querybf,
    const unsigned short* __restrict__ BcatT,
    const float* __restrict__ biascat, _Float16* __restrict__ offcat)
{
    __shared__ short8 Asl[512];   // chunk = row*4 + slot
    __shared__ short8 Bsl[512];

    // XCD-pairing dispatch remap (see header comment)
    const int d = blockIdx.x;
    int bid;
    if (d < 608) {                        // modeV: groups of 16 -> pairs
        const int base = d & ~15, o = d & 15;
        bid = base + ((o & 7) << 1) + (o >> 3);
    } else if (d < 612) {
        bid = d;                          // modeV tail
    } else if (d < 1524) {                // modeQ: groups of 48 -> sextets
        const int dd = d - 612;
        const int base = (dd / 48) * 48, o = dd - base;
        bid = 612 + base + (o & 7) * 6 + (o >> 3);
    } else {
        bid = d;                          // modeQ tail
    }

    const bool modeV = bid < 612;

    const unsigned short* Bt;
    const float* bias;
    int M, N, rowBase, colBase;
    if (modeV) {
        Bt = BvalT; bias = b_value;
        M = BS * NV; N = 256;
        rowBase = (bid >> 1) * 128; colBase = (bid & 1) * 128;
    } else {
        const int b2 = bid - 612;
        Bt = BcatT; bias = biascat;
        M = BS * NQ; N = 768;
        rowBase = (b2 / 6) * 128; colBase = (b2 % 6) * 128;
    }

    const int t = threadIdx.x;
    const int w  = t >> 6;
    const int l  = t & 63;
    const int wm = (w >> 1) * 64;
    const int wn = (w & 1) * 64;
    const int row16 = l & 15;
    const int kg    = l >> 4;

    // staging geometry: chunk = issue*256 + t; row = chunk>>2; slot = t&3
    const int r0 = t >> 2;                 // issue-0 tile row; issue-1 = r0+64
    const int m_ = t & 3;                  // stored slot
    const int cs = (m_ - (r0 >> 1)) & 3;   // logical k-chunk

    // wave-uniform LDS bases (chunks); lanes land at +lane*16B
    short8* aw0 = &Asl[(w << 6)];
    short8* aw1 = &Asl[256 + (w << 6)];
    short8* bw0 = &Bsl[(w << 6)];
    short8* bw1 = &Bsl[256 + (w << 6)];

    const int arow0 = min(rowBase + r0, M - 1);        // clamp: dupes discarded
    const int arow1 = min(rowBase + r0 + 64, M - 1);
    const int brow0 = colBase + r0;                    // always in-range
    const int brow1 = brow0 + 64;

    f32x4 acc[4][4] = {};

    for (int k0 = 0; k0 < 256; k0 += 32) {
        const int kc = k0 + cs * 8;
        // B tiles: async direct-to-LDS
        glds16(Bt + (size_t)brow0 * 256 + kc, bw0);
        glds16(Bt + (size_t)brow1 * 256 + kc, bw1);
        if (modeV) {
            // A: fp32 -> bf16 reg-staged into the same swizzled layout
            #pragma unroll
            for (int jj = 0; jj < 2; jj++) {
                const int ar = jj ? arow1 : arow0;
                const float* ap = valueF + (size_t)ar * 256 + kc;
                const float4 f0 = *(const float4*)ap;
                const float4 f1 = *(const float4*)(ap + 4);
                short8 v;
                v[0] = (short)f2bf(f0.x); v[1] = (short)f2bf(f0.y);
                v[2] = (short)f2bf(f0.z); v[3] = (short)f2bf(f0.w);
                v[4] = (short)f2bf(f1.x); v[5] = (short)f2bf(f1.y);
                v[6] = (short)f2bf(f1.z); v[7] = (short)f2bf(f1.w);
                Asl[jj * 256 + t] = v;
            }
        } else {
            glds16(querybf + (size_t)arow0 * 256 + kc, aw0);
            glds16(querybf + (size_t)arow1 * 256 + kc, aw1);
        }
        __syncthreads();   // compiler drains vmcnt+lgkmcnt here

        short8 af[4], bfr[4];
        #pragma unroll
        for (int i = 0; i < 4; i++) {
            const int r = wm + i * 16 + row16;
            af[i] = Asl[r * 4 + ((kg + (r >> 1)) & 3)];
        }
        #pragma unroll
        for (int j = 0; j < 4; j++) {
            const int r = wn + j * 16 + row16;
            bfr[j] = Bsl[r * 4 + ((kg + (r >> 1)) & 3)];
        }
        #pragma unroll
        for (int i = 0; i < 4; i++)
            #pragma unroll
            for (int j = 0; j < 4; j++)
                acc[i][j] = __builtin_amdgcn_mfma_f32_16x16x32_bf16(
                    bfr[j], af[i], acc[i][j], 0, 0, 0);
        __syncthreads();
    }

    const int m16 = l & 15;
    const int q4  = (l >> 4) * 4;
    #pragma unroll
    for (int i = 0; i < 4; i++) {
        const int row = rowBase + wm + i * 16 + m16;
        if (row >= M) continue;
        #pragma unroll
        for (int j = 0; j < 4; j++) {
            const int col0 = colBase + wn + j * 16 + q4;
            const float4 bv = *(const float4*)&bias[col0];
            half4v o;
            o[0] = (_Float16)(acc[i][j][0] + bv.x);
            o[1] = (_Float16)(acc[i][j][1] + bv.y);
            o[2] = (_Float16)(acc[i][j][2] + bv.z);
            o[3] = (_Float16)(acc[i][j][3] + bv.w);
            _Float16* dst;
            if (modeV) {
                const int b   = (row >= NV) ? 1 : 0;
                const int pix = row - b * NV;
                const int h   = col0 >> 5;
                const int ch  = col0 & 31;
                dst = vproj + ((size_t)(b * NH + h) * NV + pix) * 32 + ch;
            } else {
                dst = offcat + (size_t)row * 768 + col0;
            }
            *(half4v*)dst = o;
        }
    }
}

// ---------------------------------------------------------------------------
// Fused softmax + sampling + aggregation, (b,h)-partitioned for L2 locality.
// Desc layout v2: contiguous per-lane streams -> 8 x ds_read_b128,
// SQ_LDS_BANK_CONFLICT = 0 (verified round 2).
// Phase B: depth-8 gather pipeline forced via inline-asm global_load_dwordx4
// (saddr form). Measured 61.7 us; floor model: 1.31 GB of unique 64B lines
// through the L1 miss path (L2->L1 fill + L1->VGPR return share the port)
// ~= 60-66 us -> at the hardware-path roofline for this structure.
// ---------------------------------------------------------------------------
__global__ __launch_bounds__(256, 4) void sample_kernel(
    const _Float16* __restrict__ vproj,  // (BS, NH, NV, 32) f16
    const _Float16* __restrict__ offcat, // (BS*NQ, 768) f16 off|logits
    const float* __restrict__ refpts,    // (BS, NQ, 4, 2)
    float* __restrict__ out)             // (BS*NQ, 256)
{
    const int bid = blockIdx.x;
    const int h   = bid & 7;             // XCD-affine head
    const int g   = bid >> 3;
    const int b   = g & 1;
    const int q0  = (g >> 1) * 8;
    const int t   = threadIdx.x;

    __shared__ uint2 desc[8 * 144];      // [qi][g*18 + i]

    const int qi = t >> 5, j = t & 31;
    const int qrow = b * NQ + q0 + qi;

    // ---------------- Phase A ----------------
    {
        const int lv = j >> 3, p = j & 7;

        const float logit = (float)offcat[(size_t)qrow * 768 + 512 + h * 32 + j];
        const float e = __expf(logit);       // no max-pass: |logit| small
        float ssum = e;
        #pragma unroll
        for (int s = 16; s > 0; s >>= 1) ssum += __shfl_xor(ssum, s, 32);
        const float aw = e / ssum;

        const int Wl = LVL_W[lv], Hl = LVL_H[lv], st = LVL_START[lv];
        const uint oxy = *(const uint*)(offcat + (size_t)qrow * 768 + h * 64 + j * 2);
        const float offx = (float)__builtin_bit_cast(half2v, oxy)[0];
        const float offy = (float)__builtin_bit_cast(half2v, oxy)[1];

        const int z = p & 3;
        const float rx = refpts[((size_t)qrow * 4 + z) * 2];
        const float ry = refpts[((size_t)qrow * 4 + z) * 2 + 1];

        const float x = fmaf(rx, (float)Wl, offx) - 0.5f;
        const float y = fmaf(ry, (float)Hl, offy) - 0.5f;
        const float x0f = floorf(x), y0f = floorf(y);
        const float wx = x - x0f, wy = y - y0f;
        const int x0 = (int)x0f, y0 = (int)y0f;

        const int xb = min(max(x0, 0), Wl - 2);
        const float wl = (x0 >= 0 && x0 < Wl)          ? (1.f - wx) : 0.f;
        const float wr = (x0 + 1 >= 0 && x0 + 1 < Wl)  ? wx         : 0.f;
        const float wA = (x0 == xb) ? wl : ((x0 + 1 == xb) ? wr : 0.f);
        const float wB = (x0 == xb) ? wr : ((x0 == xb + 1) ? wl : 0.f);

        const int i16 = j >> 1;              // descriptor index within stream
        const int gA0 = qi * 144 + (((j & 1) * 2) * 2) * 18 + i16;   // r=0 base

        #pragma unroll
        for (int r = 0; r < 2; r++) {
            const int yy = y0 + r;
            const float rwv = (yy >= 0 && yy < Hl)
                            ? (r ? wy : (1.f - wy)) * aw : 0.f;
            const int iy = min(max(yy, 0), Hl - 1);
            const unsigned base = (unsigned)((st + iy * Wl + xb) * 64);
            const int gb = gA0 + r * 2 * 18;               // g = (j&1)*2+r, pix 0
            desc[gb]      = make_uint2(base,      f2h_dup(wA * rwv));
            desc[gb + 18] = make_uint2(base + 64, f2h_dup(wB * rwv));
        }
    }
    __syncthreads();

    // ---------------- Phase B (asm-forced depth-8 pipeline) ----------------
    const int lane = t & 31;
    const int grp  = lane >> 3;          // (j&1, r) group (bits 3-4)
    const int pix  = (lane >> 2) & 1;    // x-column (bit 2)
    const int chq  = lane & 3;           // channel quad (bits 0-1)

    const unsigned long long slab64 =
        (unsigned long long)(const char*)(vproj + (size_t)(b * NH + h) * NV * 32);
    const unsigned laneoff = (unsigned)(chq * 16);
    const uint4* dp = (const uint4*)&desc[qi * 144 + (grp * 2 + pix) * 18];

    half2v a0 = {}, a1 = {}, a2 = {}, a3 = {};

    #define GLD(dst, voff)                                                 \
        asm volatile("global_load_dwordx4 %0, %1, %2"                      \
                     : "=v"(dst) : "v"(voff), "s"(slab64))
    #define FMA4(wreg, vv)                                                 \
        { const half2v wv_ = __builtin_bit_cast(half2v, (unsigned)(wreg)); \
          a0 += wv_ * __builtin_bit_cast(half2v, (unsigned)(vv)[0]);       \
          a1 += wv_ * __builtin_bit_cast(half2v, (unsigned)(vv)[1]);       \
          a2 += wv_ * __builtin_bit_cast(half2v, (unsigned)(vv)[2]);       \
          a3 += wv_ * __builtin_bit_cast(half2v, (unsigned)(vv)[3]); }

    #pragma unroll
    for (int hf = 0; hf < 2; hf++) {
        uint4 d4[4];                     // 8 descriptors (addr,w pairs)
        #pragma unroll
        for (int u2 = 0; u2 < 4; u2++) d4[u2] = dp[hf * 4 + u2];
        uintx4 v0, v1, v2, v3, v4, v5, v6, v7;
        GLD(v0, d4[0].x + laneoff);
        GLD(v1, d4[0].z + laneoff);
        GLD(v2, d4[1].x + laneoff);
        GLD(v3, d4[1].z + laneoff);
        GLD(v4, d4[2].x + laneoff);
        GLD(v5, d4[2].z + laneoff);
        GLD(v6, d4[3].x + laneoff);
        GLD(v7, d4[3].z + laneoff);
        asm volatile("s_waitcnt vmcnt(4)" ::: "memory");
        __builtin_amdgcn_sched_barrier(0);
        FMA4(d4[0].y, v0); FMA4(d4[0].w, v1);
        FMA4(d4[1].y, v2); FMA4(d4[1].w, v3);
        asm volatile("s_waitcnt vmcnt(0)" ::: "memory");
        __builtin_amdgcn_sched_barrier(0);
        FMA4(d4[2].y, v4); FMA4(d4[2].w, v5);
        FMA4(d4[3].y, v6); FMA4(d4[3].w, v7);
    }
    #undef GLD
    #undef FMA4

    // packed f16 reduce over bits 2,3,4 (pix + grp)
    #pragma unroll
    for (int s = 4; s <= 16; s <<= 1) {
        a0 += __builtin_bit_cast(half2v,
              __shfl_xor(__builtin_bit_cast(unsigned, a0), s, 32));
        a1 += __builtin_bit_cast(half2v,
              __shfl_xor(__builtin_bit_cast(unsigned, a1), s, 32));
        a2 += __builtin_bit_cast(half2v,
              __shfl_xor(__builtin_bit_cast(unsigned, a2), s, 32));
        a3 += __builtin_bit_cast(half2v,
              __shfl_xor(__builtin_bit_cast(unsigned, a3), s, 32));
    }

    if ((lane & 0x1C) == 0) {            // lanes 0..3 = chq
        float* op = out + (size_t)qrow * 256 + h * 32 + chq * 8;
        *(float4*)op = make_float4((float)a0[0], (float)a0[1],
                                   (float)a1[0], (float)a1[1]);
        *(float4*)(op + 4) = make_float4((float)a2[0], (float)a2[1],
                                         (float)a3[0], (float)a3[1]);
    }
}

// ---------------------------------------------------------------------------
extern "C" void kernel_launch(void* const* d_in, const int* in_sizes, int n_in,
                              void* d_out, int out_size, void* d_ws, size_t ws_size,
                              hipStream_t stream)
{
    const float* query   = (const float*)d_in[0];
    const float* value   = (const float*)d_in[1];
    const float* refpts  = (const float*)d_in[2];
    const float* W_value = (const float*)d_in[4];
    const float* b_value = (const float*)d_in[5];
    const float* W_off   = (const float*)d_in[6];
    const float* b_off   = (const float*)d_in[7];
    const float* W_attn  = (const float*)d_in[8];
    const float* b_attn  = (const float*)d_in[9];

    char* ws = (char*)d_ws;                       // total ~61.5 MB
    _Float16*       vproj   = (_Float16*)(ws);                    // 20,029,440
    unsigned short* querybf = (unsigned short*)(ws + 20029440);   // 10,240,000
    _Float16*       offcat  = (_Float16*)(ws + 30269440);         // 30,720,000
    unsigned short* BvalT   = (unsigned short*)(ws + 60989440);   //    131,072
    unsigned short* BcatT   = (unsigned short*)(ws + 61120512);   //    393,216
    float*          biascat = (float*)(ws + 61513728);            //      3,072

    const dim3 blk(256);

    prep_all<<<dim3(6025), blk, 0, stream>>>(
        query, W_value, W_off, b_off, W_attn, b_attn,
        querybf, BvalT, BcatT, biascat);

    gemm_all<<<dim3(1554), blk, 0, stream>>>(
        value, BvalT, b_value, vproj,
        querybf, BcatT, biascat, offcat);

    sample_kernel<<<dim3(BS * NQ), blk, 0, stream>>>(
        vproj, offcat, refpts, (float*)d_out);
}

// Round 7
// 195.524 us; speedup vs baseline: 1.0837x; 1.0015x over previous
//
#include <hip/hip_runtime.h>
#include <math.h>

#define NH 8
#define NL 4
#define NP 8
#define CDIM 256
#define NQ 10000
#define BS 2
#define NV 19560

__constant__ int LVL_H[NL]     = {92, 46, 23, 12};
__constant__ int LVL_W[NL]     = {160, 80, 40, 20};
__constant__ int LVL_START[NL] = {0, 14720, 18400, 19320};

typedef __attribute__((ext_vector_type(8))) short short8;
typedef __attribute__((ext_vector_type(4))) float f32x4;
typedef __attribute__((ext_vector_type(2))) _Float16 half2v;
typedef __attribute__((ext_vector_type(4))) _Float16 half4v;
typedef __attribute__((ext_vector_type(4))) unsigned uintx4;

__device__ __forceinline__ unsigned short f2bf(float f) {
    unsigned int u = __float_as_uint(f);
    u += 0x7fffu + ((u >> 16) & 1u);   // RNE
    return (unsigned short)(u >> 16);
}

__device__ __forceinline__ unsigned f2h_dup(float f) {
    const unsigned short h = __builtin_bit_cast(unsigned short, (_Float16)f);
    return (unsigned)h | ((unsigned)h << 16);
}

// async global->LDS, 16B per lane, linear LDS dest (wave base + lane*16)
__device__ __forceinline__ void glds16(const void* g, void* l) {
    __builtin_amdgcn_global_load_lds(
        (const __attribute__((address_space(1))) unsigned*)g,
        (__attribute__((address_space(3))) unsigned*)l, 16, 0, 0);
}

// ---------------------------------------------------------------------------
// Prep: query->bf16 (blocks [0,5000)) + weight transpose/concat ([5000,6025)).
// value is converted inline in the GEMM (saves its HBM round trip).
// ---------------------------------------------------------------------------
__global__ __launch_bounds__(256) void prep_all(
    const float* __restrict__ query,
    const float* __restrict__ Wv,
    const float* __restrict__ Woff, const float* __restrict__ boff,
    const float* __restrict__ Wattn, const float* __restrict__ battn,
    unsigned short* __restrict__ querybf,
    unsigned short* __restrict__ BvalT, unsigned short* __restrict__ BcatT,
    float* __restrict__ biascat)
{
    const int bid = blockIdx.x;
    const int t   = threadIdx.x;
    if (bid < 5000) {
        const int i = bid * 256 + t;
        const float4 f = ((const float4*)query)[i];
        ushort4 o;
        o.x = f2bf(f.x); o.y = f2bf(f.y); o.z = f2bf(f.z); o.w = f2bf(f.w);
        ((ushort4*)querybf)[i] = o;
    } else {
        const int n = bid - 5000;
        if (n < 256) {
            BvalT[n * 256 + t] = f2bf(Wv[t * 256 + n]);
        } else if (n < 1024) {
            const int m = n - 256;
            const float v = (m < 512) ? Woff[t * 512 + m]
                                      : Wattn[t * 256 + (m - 512)];
            BcatT[m * 256 + t] = f2bf(v);
        } else {
            #pragma unroll
            for (int s = 0; s < 3; s++) {
                const int i = s * 256 + t;
                biascat[i] = (i < 512) ? boff[i] : battn[i - 512];
            }
        }
    }
}

// ---------------------------------------------------------------------------
// BOTH GEMMs in one dispatch. 128x128 tile, BK=64 (4 K-steps; round-6 had
// BK=32/8 steps -- the per-step __syncthreads vmcnt(0) drain was ~2/3 of gemm
// time at K=256, so halve the barrier count). Compute per step is two
// barrier-free sub-phases (h=0/1: 8 ds_read_b128 + 16 MFMA) -> frag VGPR
// stays 32. MFMA k-order unchanged -> bitwise-identical output.
// LDS: [128 rows][8 chunks of 8 bf16], slot swizzle s=(c+(r>>1))&7 ->
// ds_read_b128 exactly 8 dwords/bank (conflict-free minimum). Staging:
// store slot t&7, logical chunk cs=((t&7)-(t>>4))&7 (uniform across the 4
// 256-chunk issues), glds source carries the inverse swizzle.
// blocks [0,612): A = value (fp32, inline cvt, reg-staged) -> f16 vproj
// blocks [612,1554): A = querybf (bf16, glds) @ BcatT -> f16 offcat (row,768)
// Dispatch->logical bid remap (round 6, kept): panel-sharing blocks placed 8
// dispatch ids apart = same XCD -> re-reads hit per-XCD L2. Bijective.
// ---------------------------------------------------------------------------
__global__ __launch_bounds__(256) void gemm_all(
    const float* __restrict__ valueF,
    const unsigned short* __restrict__ BvalT,
    const float* __restrict__ b_value, _Float16* __restrict__ vproj,
    const unsigned short* __restrict__ querybf,
    const unsigned short* __restrict__ BcatT,
    const float* __restrict__ biascat, _Float16* __restrict__ offcat)
{
    __shared__ short8 Asl[1024];   // chunk = row*8 + slot
    __shared__ short8 Bsl[1024];

    // XCD-pairing dispatch remap (see header comment)
    const int d = blockIdx.x;
    int bid;
    if (d < 608) {                        // modeV: groups of 16 -> pairs
        const int base = d & ~15, o = d & 15;
        bid = base + ((o & 7) << 1) + (o >> 3);
    } else if (d < 612) {
        bid = d;                          // modeV tail
    } else if (d < 1524) {                // modeQ: groups of 48 -> sextets
        const int dd = d - 612;
        const int base = (dd / 48) * 48, o = dd - base;
        bid = 612 + base + (o & 7) * 6 + (o >> 3);
    } else {
        bid = d;                          // modeQ tail
    }

    const bool modeV = bid < 612;

    const unsigned short* Bt;
    const float* bias;
    int M, N, rowBase, colBase;
    if (modeV) {
        Bt = BvalT; bias = b_value;
        M = BS * NV; N = 256;
        rowBase = (bid >> 1) * 128; colBase = (bid & 1) * 128;
    } else {
        const int b2 = bid - 612;
        Bt = BcatT; bias = biascat;
        M = BS * NQ; N = 768;
        rowBase = (b2 / 6) * 128; colBase = (b2 % 6) * 128;
    }

    const int t = threadIdx.x;
    const int w  = t >> 6;
    const int l  = t & 63;
    const int wm = (w >> 1) * 64;
    const int wn = (w & 1) * 64;
    const int row16 = l & 15;
    const int kg    = l >> 4;

    // staging geometry (BK=64): chunk = issue*256 + t; row = chunk>>3;
    // stored slot = t&7; logical k-chunk cs = ((t&7) - (t>>4)) & 7
    // (row>>1 = issue*16 + (t>>4); issue*16 == 0 mod 8 -> cs issue-uniform)
    const int cs = ((t & 7) - (t >> 4)) & 7;
    const int rw = t >> 3;                 // row-within-issue-group (0..31)
    const int wb = w << 6;                 // wave-uniform chunk base (per issue)

    int arow[4], brow[4];
    #pragma unroll
    for (int ii = 0; ii < 4; ii++) {
        arow[ii] = min(rowBase + ii * 32 + rw, M - 1);   // clamp: dupes discarded
        brow[ii] = colBase + ii * 32 + rw;               // always in-range
    }

    f32x4 acc[4][4] = {};

    for (int k0 = 0; k0 < 256; k0 += 64) {
        const int kc = k0 + cs * 8;
        // B tiles: async direct-to-LDS (4 issues x 1024B/wave)
        #pragma unroll
        for (int ii = 0; ii < 4; ii++)
            glds16(Bt + (size_t)brow[ii] * 256 + kc, &Bsl[ii * 256 + wb]);
        if (modeV) {
            // A: fp32 -> bf16 reg-staged into the same swizzled layout
            #pragma unroll
            for (int ii = 0; ii < 4; ii++) {
                const float* ap = valueF + (size_t)arow[ii] * 256 + kc;
                const float4 f0 = *(const float4*)ap;
                const float4 f1 = *(const float4*)(ap + 4);
                short8 v;
                v[0] = (short)f2bf(f0.x); v[1] = (short)f2bf(f0.y);
                v[2] = (short)f2bf(f0.z); v[3] = (short)f2bf(f0.w);
                v[4] = (short)f2bf(f1.x); v[5] = (short)f2bf(f1.y);
                v[6] = (short)f2bf(f1.z); v[7] = (short)f2bf(f1.w);
                Asl[ii * 256 + t] = v;
            }
        } else {
            #pragma unroll
            for (int ii = 0; ii < 4; ii++)
                glds16(querybf + (size_t)arow[ii] * 256 + kc, &Asl[ii * 256 + wb]);
        }
        __syncthreads();   // compiler drains vmcnt+lgkmcnt here (1 per 64 k)

        #pragma unroll
        for (int h = 0; h < 2; h++) {      // two k-halves, no barrier between
            short8 af[4], bfr[4];
            #pragma unroll
            for (int i = 0; i < 4; i++) {
                const int r = wm + i * 16 + row16;
                af[i] = Asl[r * 8 + ((h * 4 + kg + (r >> 1)) & 7)];
            }
            #pragma unroll
            for (int j = 0; j < 4; j++) {
                const int r = wn + j * 16 + row16;
                bfr[j] = Bsl[r * 8 + ((h * 4 + kg + (r >> 1)) & 7)];
            }
            #pragma unroll
            for (int i = 0; i < 4; i++)
                #pragma unroll
                for (int j = 0; j < 4; j++)
                    acc[i][j] = __builtin_amdgcn_mfma_f32_16x16x32_bf16(
                        bfr[j], af[i], acc[i][j], 0, 0, 0);
        }
        __syncthreads();
    }

    const int m16 = l & 15;
    const int q4  = (l >> 4) * 4;
    #pragma unroll
    for (int i = 0; i < 4; i++) {
        const int row = rowBase + wm + i * 16 + m16;
        if (row >= M) continue;
        #pragma unroll
        for (int j = 0; j < 4; j++) {
            const int col0 = colBase + wn + j * 16 + q4;
            const float4 bv = *(const float4*)&bias[col0];
            half4v o;
            o[0] = (_Float16)(acc[i][j][0] + bv.x);
            o[1] = (_Float16)(acc[i][j][1] + bv.y);
            o[2] = (_Float16)(acc[i][j][2] + bv.z);
            o[3] = (_Float16)(acc[i][j][3] + bv.w);
            _Float16* dst;
            if (modeV) {
                const int b   = (row >= NV) ? 1 : 0;
                const int pix = row - b * NV;
                const int h   = col0 >> 5;
                const int ch  = col0 & 31;
                dst = vproj + ((size_t)(b * NH + h) * NV + pix) * 32 + ch;
            } else {
                dst = offcat + (size_t)row * 768 + col0;
            }
            *(half4v*)dst = o;
        }
    }
}

// ---------------------------------------------------------------------------
// Fused softmax + sampling + aggregation, (b,h)-partitioned for L2 locality.
// Desc layout v2: contiguous per-lane streams -> 8 x ds_read_b128,
// SQ_LDS_BANK_CONFLICT = 0 (verified round 2).
// Phase B: depth-8 gather pipeline forced via inline-asm global_load_dwordx4
// (saddr form). Measured 61.3 us over 3 structurally different ILP attacks;
// floor model: 1.31 GB of unique 64B lines through the L1 miss path ~= 60-66
// us -> at the hardware-path roofline for this structure. FROZEN.
// ---------------------------------------------------------------------------
__global__ __launch_bounds__(256, 4) void sample_kernel(
    const _Float16* __restrict__ vproj,  // (BS, NH, NV, 32) f16
    const _Float16* __restrict__ offcat, // (BS*NQ, 768) f16 off|logits
    const float* __restrict__ refpts,    // (BS, NQ, 4, 2)
    float* __restrict__ out)             // (BS*NQ, 256)
{
    const int bid = blockIdx.x;
    const int h   = bid & 7;             // XCD-affine head
    const int g   = bid >> 3;
    const int b   = g & 1;
    const int q0  = (g >> 1) * 8;
    const int t   = threadIdx.x;

    __shared__ uint2 desc[8 * 144];      // [qi][g*18 + i]

    const int qi = t >> 5, j = t & 31;
    const int qrow = b * NQ + q0 + qi;

    // ---------------- Phase A ----------------
    {
        const int lv = j >> 3, p = j & 7;

        const float logit = (float)offcat[(size_t)qrow * 768 + 512 + h * 32 + j];
        const float e = __expf(logit);       // no max-pass: |logit| small
        float ssum = e;
        #pragma unroll
        for (int s = 16; s > 0; s >>= 1) ssum += __shfl_xor(ssum, s, 32);
        const float aw = e / ssum;

        const int Wl = LVL_W[lv], Hl = LVL_H[lv], st = LVL_START[lv];
        const uint oxy = *(const uint*)(offcat + (size_t)qrow * 768 + h * 64 + j * 2);
        const float offx = (float)__builtin_bit_cast(half2v, oxy)[0];
        const float offy = (float)__builtin_bit_cast(half2v, oxy)[1];

        const int z = p & 3;
        const float rx = refpts[((size_t)qrow * 4 + z) * 2];
        const float ry = refpts[((size_t)qrow * 4 + z) * 2 + 1];

        const float x = fmaf(rx, (float)Wl, offx) - 0.5f;
        const float y = fmaf(ry, (float)Hl, offy) - 0.5f;
        const float x0f = floorf(x), y0f = floorf(y);
        const float wx = x - x0f, wy = y - y0f;
        const int x0 = (int)x0f, y0 = (int)y0f;

        const int xb = min(max(x0, 0), Wl - 2);
        const float wl = (x0 >= 0 && x0 < Wl)          ? (1.f - wx) : 0.f;
        const float wr = (x0 + 1 >= 0 && x0 + 1 < Wl)  ? wx         : 0.f;
        const float wA = (x0 == xb) ? wl : ((x0 + 1 == xb) ? wr : 0.f);
        const float wB = (x0 == xb) ? wr : ((x0 == xb + 1) ? wl : 0.f);

        const int i16 = j >> 1;              // descriptor index within stream
        const int gA0 = qi * 144 + (((j & 1) * 2) * 2) * 18 + i16;   // r=0 base

        #pragma unroll
        for (int r = 0; r < 2; r++) {
            const int yy = y0 + r;
            const float rwv = (yy >= 0 && yy < Hl)
                            ? (r ? wy : (1.f - wy)) * aw : 0.f;
            const int iy = min(max(yy, 0), Hl - 1);
            const unsigned base = (unsigned)((st + iy * Wl + xb) * 64);
            const int gb = gA0 + r * 2 * 18;               // g = (j&1)*2+r, pix 0
            desc[gb]      = make_uint2(base,      f2h_dup(wA * rwv));
            desc[gb + 18] = make_uint2(base + 64, f2h_dup(wB * rwv));
        }
    }
    __syncthreads();

    // ---------------- Phase B (asm-forced depth-8 pipeline) ----------------
    const int lane = t & 31;
    const int grp  = lane >> 3;          // (j&1, r) group (bits 3-4)
    const int pix  = (lane >> 2) & 1;    // x-column (bit 2)
    const int chq  = lane & 3;           // channel quad (bits 0-1)

    const unsigned long long slab64 =
        (unsigned long long)(const char*)(vproj + (size_t)(b * NH + h) * NV * 32);
    const unsigned laneoff = (unsigned)(chq * 16);
    const uint4* dp = (const uint4*)&desc[qi * 144 + (grp * 2 + pix) * 18];

    half2v a0 = {}, a1 = {}, a2 = {}, a3 = {};

    #define GLD(dst, voff)                                                 \
        asm volatile("global_load_dwordx4 %0, %1, %2"                      \
                     : "=v"(dst) : "v"(voff), "s"(slab64))
    #define FMA4(wreg, vv)                                                 \
        { const half2v wv_ = __builtin_bit_cast(half2v, (unsigned)(wreg)); \
          a0 += wv_ * __builtin_bit_cast(half2v, (unsigned)(vv)[0]);       \
          a1 += wv_ * __builtin_bit_cast(half2v, (unsigned)(vv)[1]);       \
          a2 += wv_ * __builtin_bit_cast(half2v, (unsigned)(vv)[2]);       \
          a3 += wv_ * __builtin_bit_cast(half2v, (unsigned)(vv)[3]); }

    #pragma unroll
    for (int hf = 0; hf < 2; hf++) {
        uint4 d4[4];                     // 8 descriptors (addr,w pairs)
        #pragma unroll
        for (int u2 = 0; u2 < 4; u2++) d4[u2] = dp[hf * 4 + u2];
        uintx4 v0, v1, v2, v3, v4, v5, v6, v7;
        GLD(v0, d4[0].x + laneoff);
        GLD(v1, d4[0].z + laneoff);
        GLD(v2, d4[1].x + laneoff);
        GLD(v3, d4[1].z + laneoff);
        GLD(v4, d4[2].x + laneoff);
        GLD(v5, d4[2].z + laneoff);
        GLD(v6, d4[3].x + laneoff);
        GLD(v7, d4[3].z + laneoff);
        asm volatile("s_waitcnt vmcnt(4)" ::: "memory");
        __builtin_amdgcn_sched_barrier(0);
        FMA4(d4[0].y, v0); FMA4(d4[0].w, v1);
        FMA4(d4[1].y, v2); FMA4(d4[1].w, v3);
        asm volatile("s_waitcnt vmcnt(0)" ::: "memory");
        __builtin_amdgcn_sched_barrier(0);
        FMA4(d4[2].y, v4); FMA4(d4[2].w, v5);
        FMA4(d4[3].y, v6); FMA4(d4[3].w, v7);
    }
    #undef GLD
    #undef FMA4

    // packed f16 reduce over bits 2,3,4 (pix + grp)
    #pragma unroll
    for (int s = 4; s <= 16; s <<= 1) {
        a0 += __builtin_bit_cast(half2v,
              __shfl_xor(__builtin_bit_cast(unsigned, a0), s, 32));
        a1 += __builtin_bit_cast(half2v,
              __shfl_xor(__builtin_bit_cast(unsigned, a1), s, 32));
        a2 += __builtin_bit_cast(half2v,
              __shfl_xor(__builtin_bit_cast(unsigned, a2), s, 32));
        a3 += __builtin_bit_cast(half2v,
              __shfl_xor(__builtin_bit_cast(unsigned, a3), s, 32));
    }

    if ((lane & 0x1C) == 0) {            // lanes 0..3 = chq
        float* op = out + (size_t)qrow * 256 + h * 32 + chq * 8;
        *(float4*)op = make_float4((float)a0[0], (float)a0[1],
                                   (float)a1[0], (float)a1[1]);
        *(float4*)(op + 4) = make_float4((float)a2[0], (float)a2[1],
                                         (float)a3[0], (float)a3[1]);
    }
}

// ---------------------------------------------------------------------------
extern "C" void kernel_launch(void* const* d_in, const int* in_sizes, int n_in,
                              void* d_out, int out_size, void* d_ws, size_t ws_size,
                              hipStream_t stream)
{
    const float* query   = (const float*)d_in[0];
    const float* value   = (const float*)d_in[1];
    const float* refpts  = (const float*)d_in[2];
    const float* W_value = (const float*)d_in[4];
    const float* b_value = (const float*)d_in[5];
    const float* W_off   = (const float*)d_in[6];
    const float* b_off   = (const float*)d_in[7];
    const float* W_attn  = (const float*)d_in[8];
    const float* b_attn  = (const float*)d_in[9];

    char* ws = (char*)d_ws;                       // total ~61.5 MB
    _Float16*       vproj   = (_Float16*)(ws);                    // 20,029,440
    unsigned short* querybf = (unsigned short*)(ws + 20029440);   // 10,240,000
    _Float16*       offcat  = (_Float16*)(ws + 30269440);         // 30,720,000
    unsigned short* BvalT   = (unsigned short*)(ws + 60989440);   //    131,072
    unsigned short* BcatT   = (unsigned short*)(ws + 61120512);   //    393,216
    float*          biascat = (float*)(ws + 61513728);            //      3,072

    const dim3 blk(256);

    prep_all<<<dim3(6025), blk, 0, stream>>>(
        query, W_value, W_off, b_off, W_attn, b_attn,
        querybf, BvalT, BcatT, biascat);

    gemm_all<<<dim3(1554), blk, 0, stream>>>(
        value, BvalT, b_value, vproj,
        querybf, BcatT, biascat, offcat);

    sample_kernel<<<dim3(BS * NQ), blk, 0, stream>>>(
        vproj, offcat, refpts, (float*)d_out);
}